// Round 3
// baseline (1033.256 us; speedup 1.0000x reference)
//
#include <hip/hip_runtime.h>
#include <hip/hip_cooperative_groups.h>

namespace cg = cooperative_groups;

typedef __attribute__((ext_vector_type(8))) short short8;
typedef __attribute__((ext_vector_type(4))) float f32x4;
typedef __attribute__((ext_vector_type(4))) float fvec4;
typedef __attribute__((ext_vector_type(4))) unsigned short us4;

#define T_ 2048
#define D_ 512
#define SC_ 0.04419417382415922f   // 1/sqrt(512)

__device__ __forceinline__ unsigned short f2bf(float f) {
    unsigned int u = __float_as_uint(f);
    u += 0x7fffu + ((u >> 16) & 1u);
    return (unsigned short)(u >> 16);
}

// async global->LDS, 16B per lane; LDS dest = wave-uniform base + lane*16
__device__ __forceinline__ void gload16(const void* g, void* l) {
    __builtin_amdgcn_global_load_lds((const __attribute__((address_space(1))) unsigned int*)g,
                                     (__attribute__((address_space(3))) unsigned int*)l,
                                     16, 0, 0);
}

// ---------------------------------------------------------------- prep kernels
__global__ __launch_bounds__(256) void prep_convert(const float* __restrict__ in,
                                                    unsigned short* __restrict__ out,
                                                    int* __restrict__ ctrs) {
    if (blockIdx.x == 0 && threadIdx.x < 8) ctrs[threadIdx.x] = 0;  // work-steal counters
    const int idx = blockIdx.x * 256 + threadIdx.x;
    fvec4 v = ((const fvec4*)in)[idx];
    us4 o;
    o.x = f2bf(v.x); o.y = f2bf(v.y); o.z = f2bf(v.z); o.w = f2bf(v.w);
    ((us4*)out)[idx] = o;
}

__global__ __launch_bounds__(256) void prep_w(const float* __restrict__ W0, const float* __restrict__ W1,
                                              const float* __restrict__ W2, const float* __restrict__ W3,
                                              unsigned short* __restrict__ T0, unsigned short* __restrict__ T1,
                                              unsigned short* __restrict__ T2, unsigned short* __restrict__ T3) {
    const int o = blockIdx.x * 256 + threadIdx.x;
    const int c = o >> 9, r = o & 511;               // WT[c][r] = W[r][c]
    const float* W = (blockIdx.y == 0) ? W0 : (blockIdx.y == 1) ? W1 : (blockIdx.y == 2) ? W2 : W3;
    unsigned short* Tp = (blockIdx.y == 0) ? T0 : (blockIdx.y == 1) ? T1 : (blockIdx.y == 2) ? T2 : T3;
    Tp[o] = f2bf(W[r * 512 + c]);
}

__global__ __launch_bounds__(256) void prep_pe(unsigned short* __restrict__ pe) {
    const int o = blockIdx.x * 256 + threadIdx.x;
    const int rpos = o >> 9;
    const int c = o & 511;
    const int ci = (c < 256) ? c : c - 256;
    const float sf = -0.03611898183128701f;          // -log(10000)/255
    const float dv = expf((float)ci * sf);
    const float ang = (float)rpos * dv;
    const float v = (c < 256) ? sinf(ang) : cosf(ang);
    pe[o] = f2bf(v);
}

// ---------------------------------------------------------------- mega kernel
struct __align__(16) SMem {
    unsigned short At[128 * 32];   // 8 KB (softmax reuses as float s[2048])
    unsigned short Bt[128 * 32];   // 8 KB
    float red[8];
    int jobS;
};

// acc += A_tile(128xK) * B_tile(128xK)^T, tiles staged via global_load_lds
__device__ __forceinline__ void gemm_core(const unsigned short* __restrict__ A, long lda,
                                          const unsigned short* __restrict__ B, long ldb,
                                          int kmax, SMem& sm, f32x4 (&acc)[4][4]) {
    const int tid = threadIdx.x;
    const int wid = tid >> 6;
    const int lane = tid & 63;
    const int quad = lane >> 4;
    const int lr = lane & 15;
    const int wm = (wid & 1) * 64;
    const int wn = (wid >> 1) * 64;
#pragma unroll
    for (int r = 0; r < 4; ++r)
#pragma unroll
        for (int c = 0; c < 4; ++c) acc[r][c] = (f32x4){0.f, 0.f, 0.f, 0.f};

    const int sr = tid >> 2;
    const int sc = (tid & 3) * 8;
    const unsigned short* Ag = A + (long)sr * lda + sc;
    const unsigned short* Bg = B + (long)sr * ldb + sc;
    unsigned short* lA0 = &sm.At[wid * 512];
    unsigned short* lA1 = &sm.At[2048 + wid * 512];
    unsigned short* lB0 = &sm.Bt[wid * 512];
    unsigned short* lB1 = &sm.Bt[2048 + wid * 512];

    for (int kk = 0; kk < kmax; kk += 32) {
        gload16(Ag + kk, lA0);
        gload16(Ag + 64L * lda + kk, lA1);
        gload16(Bg + kk, lB0);
        gload16(Bg + 64L * ldb + kk, lB1);
        __syncthreads();
        short8 av[4], bv[4];
#pragma unroll
        for (int r = 0; r < 4; ++r)
            av[r] = *(const short8*)&sm.At[(wm + r * 16 + lr) * 32 + quad * 8];
#pragma unroll
        for (int c = 0; c < 4; ++c)
            bv[c] = *(const short8*)&sm.Bt[(wn + c * 16 + lr) * 32 + quad * 8];
#pragma unroll
        for (int r = 0; r < 4; ++r)
#pragma unroll
            for (int c = 0; c < 4; ++c)
                acc[r][c] = __builtin_amdgcn_mfma_f32_16x16x32_bf16(av[r], bv[c], acc[r][c], 0, 0, 0);
        __syncthreads();
    }
}

#define JOB_LOOP(PH, NJOBS)                                         \
    for (;;) {                                                      \
        __syncthreads();                                            \
        if (threadIdx.x == 0) sm.jobS = atomicAdd(&ctrs[PH], 1);    \
        __syncthreads();                                            \
        const int t = sm.jobS;                                      \
        if (t >= (NJOBS)) break;

#define JOB_END }

__global__ __launch_bounds__(256) void mega(
    const unsigned short* __restrict__ in_bf,
    const unsigned short* __restrict__ WqT, const unsigned short* __restrict__ WkT,
    const unsigned short* __restrict__ WvT, const unsigned short* __restrict__ WrT,
    const unsigned short* __restrict__ pe,
    const float* __restrict__ cb, const float* __restrict__ rb,
    unsigned short* __restrict__ qc, unsigned short* __restrict__ qr,
    unsigned short* __restrict__ kbf, unsigned short* __restrict__ vT,
    unsigned short* __restrict__ rk,
    float* __restrict__ C8, float* __restrict__ out,
    int* __restrict__ ctrs)
{
    __shared__ SMem sm;
    cg::grid_group grid = cg::this_grid();
    const int tid = threadIdx.x;
    const int wid = tid >> 6;
    const int lane = tid & 63;
    const int quad = lane >> 4;
    const int lr = lane & 15;
    const int wm = (wid & 1) * 64;
    const int wn = (wid >> 1) * 64;
    const long TD = (long)T_ * D_;     // 1048576
    const long DT = (long)D_ * T_;
    f32x4 acc[4][4];

    // ---- phase 0: projections (qc/qr, k, vT, rk) — 1600 tile jobs
    JOB_LOOP(0, 1600)
        if (t < 1024) {                           // qc/qr (t<512) and k (t<1024)
            const int r = t & 511;
            const int it = r >> 2, jt = r & 3;
            const unsigned short* Bw = (t < 512) ? WqT : WkT;
            gemm_core(in_bf + (long)it * 128 * 512, 512, Bw + (long)jt * 128 * 512, 512, 512, sm, acc);
            const int i0 = it * 128, j0 = jt * 128;
#pragma unroll
            for (int r2 = 0; r2 < 4; ++r2)
#pragma unroll
                for (int c2 = 0; c2 < 4; ++c2) {
                    const int gi = i0 + wm + r2 * 16 + quad * 4;
                    const int gj = j0 + wn + c2 * 16 + lr;
#pragma unroll
                    for (int tt = 0; tt < 4; ++tt) {
                        const float v = acc[r2][c2][tt];
                        const long row = gi + tt;
                        if (t < 512) {
                            qc[row * 512 + gj] = f2bf(v + cb[gj]);
                            qr[row * 512 + gj] = f2bf(v + rb[gj]);
                        } else {
                            kbf[row * 512 + gj] = f2bf(v);
                        }
                    }
                }
        } else if (t < 1536) {                    // vT[b] = Wv^T @ in[b]^T
            const int r = t - 1024;
            const int z = r >> 6, rr = r & 63;
            const int it = rr >> 4, jt = rr & 15;
            const int i0 = it * 128, j0 = jt * 128;
            gemm_core(WvT + (long)i0 * 512, 512, in_bf + (long)z * TD + (long)j0 * 512, 512, 512, sm, acc);
#pragma unroll
            for (int r2 = 0; r2 < 4; ++r2)
#pragma unroll
                for (int c2 = 0; c2 < 4; ++c2) {
                    const int gi = i0 + wm + r2 * 16 + quad * 4;
                    const int gj = j0 + wn + c2 * 16 + lr;
#pragma unroll
                    for (int tt = 0; tt < 4; ++tt)
                        vT[(long)z * DT + (long)(gi + tt) * 2048 + gj] = f2bf(acc[r2][c2][tt]);
                }
        } else {                                  // rk = pe @ Wrel
            const int r = t - 1536;
            const int it = r >> 2, jt = r & 3;
            const int i0 = it * 128, j0 = jt * 128;
            gemm_core(pe + (long)i0 * 512, 512, WrT + (long)j0 * 512, 512, 512, sm, acc);
#pragma unroll
            for (int r2 = 0; r2 < 4; ++r2)
#pragma unroll
                for (int c2 = 0; c2 < 4; ++c2) {
                    const int gi = i0 + wm + r2 * 16 + quad * 4;
                    const int gj = j0 + wn + c2 * 16 + lr;
#pragma unroll
                    for (int tt = 0; tt < 4; ++tt)
                        rk[(long)(gi + tt) * 512 + gj] = f2bf(acc[r2][c2][tt]);
                }
        }
    JOB_END
    __threadfence(); grid.sync(); __threadfence();

    // ---- phase 1a: content scores, causal tiles (8 x 136 jobs)
    JOB_LOOP(1, 1088)
        const int z = t / 136;
        const int r = t - z * 136;
        int a = (int)((sqrtf(8.f * (float)r + 1.f) - 1.f) * 0.5f);
        if ((a + 1) * (a + 2) / 2 <= r) ++a;
        if (a * (a + 1) / 2 > r) --a;
        const int b = r - a * (a + 1) / 2;        // b <= a
        const int i0 = a * 128, j0 = b * 128;
        gemm_core(qc + (long)z * TD + (long)i0 * 512, 512,
                  kbf + (long)z * TD + (long)j0 * 512, 512, 512, sm, acc);
        float* Cf = C8 + (long)z * 4194304L;
#pragma unroll
        for (int r2 = 0; r2 < 4; ++r2)
#pragma unroll
            for (int c2 = 0; c2 < 4; ++c2) {
                const int gi = i0 + wm + r2 * 16 + quad * 4;
                const int gj = j0 + wn + c2 * 16 + lr;
#pragma unroll
                for (int tt = 0; tt < 4; ++tt)
                    Cf[(long)(gi + tt) * 2048 + gj] = acc[r2][c2][tt] * SC_;
            }
    JOB_END
    __threadfence(); grid.sync(); __threadfence();

    // ---- phase 1b: relative scores, shift-scatter-add (8 x 136 jobs)
    JOB_LOOP(2, 1088)
        const int z = t / 136;
        const int r = t - z * 136;
        int u = (int)((sqrtf(8.f * (float)r + 1.f) - 1.f) * 0.5f);
        if ((u + 1) * (u + 2) / 2 <= r) ++u;
        if (u * (u + 1) / 2 > r) --u;
        const int v2 = r - u * (u + 1) / 2;       // v2 <= u
        const int a = u, b = 15 - u + v2;         // a+b >= 15 (tiles with shift targets)
        const int i0 = a * 128, p0 = b * 128;
        gemm_core(qr + (long)z * TD + (long)i0 * 512, 512,
                  rk + (long)p0 * 512, 512, 512, sm, acc);
        float* Cf = C8 + (long)z * 4194304L;
#pragma unroll
        for (int r2 = 0; r2 < 4; ++r2)
#pragma unroll
            for (int c2 = 0; c2 < 4; ++c2) {
                const int gi = i0 + wm + r2 * 16 + quad * 4;
                const int gp = p0 + wn + c2 * 16 + lr;
#pragma unroll
                for (int tt = 0; tt < 4; ++tt) {
                    const int row = gi + tt;
                    const int j = row + gp - (T_ - 1);   // R[i,p] -> C[i, i+p-(T-1)]
                    if (j >= 0) Cf[(long)row * 2048 + j] += acc[r2][c2][tt] * SC_;
                }
            }
    JOB_END
    __threadfence(); grid.sync(); __threadfence();

    // ---- phase 2: row softmax -> P (bf16 in place), 16384 row jobs
    JOB_LOOP(3, 16384)
        const int z = t >> 11;
        const int i = t & 2047;
        const int n = i + 1;
        float* Cm = C8 + (long)z * 4194304L;
        float* row = Cm + (long)i * 2048;
        float* s = (float*)sm.At;                 // 2048 floats, reuses staging LDS
        float lmax = -3.0e38f;
        for (int j = tid; j < n; j += 256) { float v = row[j]; s[j] = v; lmax = fmaxf(lmax, v); }
        for (int o = 32; o; o >>= 1) lmax = fmaxf(lmax, __shfl_down(lmax, o));
        if (lane == 0) sm.red[wid] = lmax;
        __syncthreads();
        if (tid == 0) sm.red[4] = fmaxf(fmaxf(sm.red[0], sm.red[1]), fmaxf(sm.red[2], sm.red[3]));
        __syncthreads();
        const float m = sm.red[4];
        float lsum = 0.f;
        for (int j = tid; j < n; j += 256) { float e = __expf(s[j] - m); s[j] = e; lsum += e; }
        for (int o = 32; o; o >>= 1) lsum += __shfl_down(lsum, o);
        __syncthreads();
        if (lane == 0) sm.red[wid] = lsum;
        __syncthreads();
        if (tid == 0) sm.red[4] = 1.0f / (sm.red[0] + sm.red[1] + sm.red[2] + sm.red[3]);
        __syncthreads();
        const float inv = sm.red[4];
        unsigned short* P = (unsigned short*)Cm;  // bf16 row stride 4096
        const int iend = ((i >> 7) + 1) << 7;     // zero-pad to 128-tile edge
        for (int j = tid; j < iend; j += 256) {
            const float pv = (j < n) ? s[j] * inv : 0.f;
            P[(long)i * 4096 + j] = f2bf(pv);
        }
        __syncthreads();                          // s[] reused by next job
    JOB_END
    __threadfence(); grid.sync(); __threadfence();

    // ---- phase 3: out = P @ V, 512 jobs, largest-K first
    JOB_LOOP(4, 512)
        const int z = t >> 6;
        const int rr = t & 63;
        const int it = 15 - (rr >> 2);            // big kmax pulled first
        const int jt = rr & 3;
        const int i0 = it * 128, j0 = jt * 128;
        const int kmax = i0 + 128;
        gemm_core((const unsigned short*)(C8 + (long)z * 4194304L) + (long)i0 * 4096, 4096,
                  vT + (long)z * DT + (long)j0 * 2048, 2048, kmax, sm, acc);
#pragma unroll
        for (int r2 = 0; r2 < 4; ++r2)
#pragma unroll
            for (int c2 = 0; c2 < 4; ++c2) {
                const int gi = i0 + wm + r2 * 16 + quad * 4;
                const int gj = j0 + wn + c2 * 16 + lr;
#pragma unroll
                for (int tt = 0; tt < 4; ++tt)
                    out[(long)z * TD + (long)(gi + tt) * 512 + gj] = acc[r2][c2][tt];
            }
    JOB_END
}

// ---------------------------------------------------------------- launcher
extern "C" void kernel_launch(void* const* d_in, const int* in_sizes, int n_in,
                              void* d_out, int out_size, void* d_ws, size_t ws_size,
                              hipStream_t stream) {
    (void)in_sizes; (void)n_in; (void)out_size; (void)ws_size;
    const float* inputs = (const float*)d_in[0];
    const float* Wq = (const float*)d_in[1];
    const float* Wk = (const float*)d_in[2];
    const float* Wv = (const float*)d_in[3];
    const float* Wrel = (const float*)d_in[4];
    const float* cb = (const float*)d_in[5];
    const float* rb = (const float*)d_in[6];
    float* out = (float*)d_out;

    // workspace layout (~224 MB)
    char* ws = (char*)d_ws;
    unsigned short* in_bf = (unsigned short*)ws;                   // 16384x512
    unsigned short* WqT = (unsigned short*)(ws + 16777216);
    unsigned short* WkT = WqT + 262144;
    unsigned short* WvT = WkT + 262144;
    unsigned short* WrT = WvT + 262144;
    unsigned short* pe  = WrT + 262144;                            // 2048x512
    unsigned short* qc  = pe + 1048576;                            // 16384x512
    unsigned short* qr  = qc + 8388608;
    unsigned short* kbf = qr + 8388608;
    unsigned short* vT  = kbf + 8388608;                           // 8 x 512x2048
    unsigned short* rk  = vT + 8388608;                            // 2048x512
    float* C8 = (float*)(rk + 1048576);                            // 8 x 2048x2048 f32
    int* ctrs = (int*)((char*)C8 + 134217728);                     // 8 ints

    prep_convert<<<dim3(8192), 256, 0, stream>>>(inputs, in_bf, ctrs);
    prep_w<<<dim3(1024, 4), 256, 0, stream>>>(Wq, Wk, Wv, Wrel, WqT, WkT, WvT, WrT);
    prep_pe<<<dim3(4096), 256, 0, stream>>>(pe);

    int occ = 0;
    hipError_t e = hipOccupancyMaxActiveBlocksPerMultiprocessor(&occ, (const void*)mega, 256, 0);
    if (e != hipSuccess || occ < 1) occ = 1;
    int nblocks = occ * 256;
    if (nblocks > 2048) nblocks = 2048;

    void* args[] = {(void*)&in_bf, (void*)&WqT, (void*)&WkT, (void*)&WvT, (void*)&WrT,
                    (void*)&pe, (void*)&cb, (void*)&rb, (void*)&qc, (void*)&qr,
                    (void*)&kbf, (void*)&vT, (void*)&rk, (void*)&C8, (void*)&out,
                    (void*)&ctrs};
    hipLaunchCooperativeKernel((const void*)mega, dim3(nblocks), dim3(256), args, 0, stream);
}

// Round 4
// 446.422 us; speedup vs baseline: 2.3145x; 2.3145x over previous
//
#include <hip/hip_runtime.h>

typedef __attribute__((ext_vector_type(8))) short short8;
typedef __attribute__((ext_vector_type(4))) float f32x4;
typedef __attribute__((ext_vector_type(4))) float fvec4;
typedef __attribute__((ext_vector_type(4))) unsigned short us4;

#define T_ 2048
#define D_ 512
#define SC_ 0.04419417382415922f   // 1/sqrt(512)

__device__ __forceinline__ unsigned short f2bf(float f) {
    unsigned int u = __float_as_uint(f);
    u += 0x7fffu + ((u >> 16) & 1u);
    return (unsigned short)(u >> 16);
}

// async global->LDS, 16B per lane; LDS dest = wave-uniform base + lane*16
__device__ __forceinline__ void gload16(const void* g, void* l) {
    __builtin_amdgcn_global_load_lds((const __attribute__((address_space(1))) unsigned int*)g,
                                     (__attribute__((address_space(3))) unsigned int*)l,
                                     16, 0, 0);
}

// ---------------------------------------------------------------- prep kernels
__global__ __launch_bounds__(256) void prep_convert(const float* __restrict__ in,
                                                    unsigned short* __restrict__ out) {
    const int idx = blockIdx.x * 256 + threadIdx.x;
    fvec4 v = ((const fvec4*)in)[idx];
    us4 o;
    o.x = f2bf(v.x); o.y = f2bf(v.y); o.z = f2bf(v.z); o.w = f2bf(v.w);
    ((us4*)out)[idx] = o;
}

__global__ __launch_bounds__(256) void prep_w(const float* __restrict__ W0, const float* __restrict__ W1,
                                              const float* __restrict__ W2, const float* __restrict__ W3,
                                              unsigned short* __restrict__ T0, unsigned short* __restrict__ T1,
                                              unsigned short* __restrict__ T2, unsigned short* __restrict__ T3) {
    const int o = blockIdx.x * 256 + threadIdx.x;
    const int c = o >> 9, r = o & 511;               // WT[c][r] = W[r][c]
    const float* W = (blockIdx.y == 0) ? W0 : (blockIdx.y == 1) ? W1 : (blockIdx.y == 2) ? W2 : W3;
    unsigned short* Tp = (blockIdx.y == 0) ? T0 : (blockIdx.y == 1) ? T1 : (blockIdx.y == 2) ? T2 : T3;
    Tp[o] = f2bf(W[r * 512 + c]);
}

__global__ __launch_bounds__(256) void prep_pe(unsigned short* __restrict__ pe) {
    const int o = blockIdx.x * 256 + threadIdx.x;
    const int rpos = o >> 9;
    const int c = o & 511;
    const int ci = (c < 256) ? c : c - 256;
    const float sf = -0.03611898183128701f;          // -log(10000)/255
    const float dv = expf((float)ci * sf);
    const float ang = (float)rpos * dv;
    const float v = (c < 256) ? sinf(ang) : cosf(ang);
    pe[o] = f2bf(v);
}

// ---------------------------------------------------------------- GEMM core
// LDS tile layout: element (row, c) lives in 16B chunk (row, (c/8) ^ ((row>>1)&3))
// XOR swizzle spreads ds_read_b128 across all 8 bank-groups per octet.
struct __align__(16) SMem {
    unsigned short At[128 * 32];   // 8 KB
    unsigned short Bt[128 * 32];   // 8 KB
};

__device__ __forceinline__ void gemm_core(const unsigned short* __restrict__ A, long lda,
                                          const unsigned short* __restrict__ B, long ldb,
                                          int kmax, SMem& sm, f32x4 (&acc)[4][4]) {
    const int tid = threadIdx.x;
    const int wid = tid >> 6;
    const int lane = tid & 63;
    const int quad = lane >> 4;
    const int lr = lane & 15;
    const int wm = (wid & 1) * 64;
    const int wn = (wid >> 1) * 64;
#pragma unroll
    for (int r = 0; r < 4; ++r)
#pragma unroll
        for (int c = 0; c < 4; ++c) acc[r][c] = (f32x4){0.f, 0.f, 0.f, 0.f};

    const int sr = tid >> 2;                              // staging row 0..63
    const int sc = (((tid & 3) ^ ((sr >> 1) & 3))) * 8;   // swizzled source chunk
    const unsigned short* Ag = A + (long)sr * lda + sc;
    const unsigned short* Bg = B + (long)sr * ldb + sc;
    // rows sr+64: ((sr+64)>>1)&3 == (sr>>1)&3, so same sc for the second half
    unsigned short* lA0 = &sm.At[wid * 512];
    unsigned short* lA1 = &sm.At[2048 + wid * 512];
    unsigned short* lB0 = &sm.Bt[wid * 512];
    unsigned short* lB1 = &sm.Bt[2048 + wid * 512];

    for (int kk = 0; kk < kmax; kk += 32) {
        gload16(Ag + kk, lA0);
        gload16(Ag + 64L * lda + kk, lA1);
        gload16(Bg + kk, lB0);
        gload16(Bg + 64L * ldb + kk, lB1);
        __syncthreads();
        short8 av[4], bv[4];
#pragma unroll
        for (int r = 0; r < 4; ++r) {
            const int row = wm + r * 16 + lr;
            av[r] = *(const short8*)&sm.At[row * 32 + ((quad ^ ((row >> 1) & 3)) * 8)];
        }
#pragma unroll
        for (int c = 0; c < 4; ++c) {
            const int row = wn + c * 16 + lr;
            bv[c] = *(const short8*)&sm.Bt[row * 32 + ((quad ^ ((row >> 1) & 3)) * 8)];
        }
#pragma unroll
        for (int r = 0; r < 4; ++r)
#pragma unroll
            for (int c = 0; c < 4; ++c)
                acc[r][c] = __builtin_amdgcn_mfma_f32_16x16x32_bf16(av[r], bv[c], acc[r][c], 0, 0, 0);
        __syncthreads();
    }
}

// C/D layout col=lane&15, row=quad*4+reg  [verified m89/m91]
#define EPI_COORDS()                               \
    const int tid = threadIdx.x;                   \
    const int wid = tid >> 6;                      \
    const int lane = tid & 63;                     \
    const int quad = lane >> 4;                    \
    const int lr = lane & 15;                      \
    const int wm = (wid & 1) * 64;                 \
    const int wn = (wid >> 1) * 64;

// ---------------------------------------------------------------- phase kernels
__global__ __launch_bounds__(256) void proj_kernel(
    const unsigned short* __restrict__ in_bf,
    const unsigned short* __restrict__ WqT, const unsigned short* __restrict__ WkT,
    const unsigned short* __restrict__ WvT, const unsigned short* __restrict__ WrT,
    const unsigned short* __restrict__ pe,
    const float* __restrict__ cb, const float* __restrict__ rb,
    unsigned short* __restrict__ qc, unsigned short* __restrict__ qr,
    unsigned short* __restrict__ kbf, unsigned short* __restrict__ vT,
    unsigned short* __restrict__ rk)
{
    __shared__ SMem sm;
    EPI_COORDS();
    const long TD = (long)T_ * D_;
    const long DT = (long)D_ * T_;
    f32x4 acc[4][4];
    const int t = blockIdx.x;   // 0..1599
    if (t < 1024) {                           // qc/qr (t<512) and k (t<1024)
        const int r = t & 511;
        const int it = r >> 2, jt = r & 3;
        const unsigned short* Bw = (t < 512) ? WqT : WkT;
        gemm_core(in_bf + (long)it * 128 * 512, 512, Bw + (long)jt * 128 * 512, 512, 512, sm, acc);
        const int i0 = it * 128, j0 = jt * 128;
#pragma unroll
        for (int r2 = 0; r2 < 4; ++r2)
#pragma unroll
            for (int c2 = 0; c2 < 4; ++c2) {
                const int gi = i0 + wm + r2 * 16 + quad * 4;
                const int gj = j0 + wn + c2 * 16 + lr;
#pragma unroll
                for (int tt = 0; tt < 4; ++tt) {
                    const float v = acc[r2][c2][tt];
                    const long row = gi + tt;
                    if (t < 512) {
                        qc[row * 512 + gj] = f2bf(v + cb[gj]);
                        qr[row * 512 + gj] = f2bf(v + rb[gj]);
                    } else {
                        kbf[row * 512 + gj] = f2bf(v);
                    }
                }
            }
    } else if (t < 1536) {                    // vT[b] = Wv^T @ in[b]^T
        const int r = t - 1024;
        const int z = r >> 6, rr = r & 63;
        const int it = rr >> 4, jt = rr & 15;
        const int i0 = it * 128, j0 = jt * 128;
        gemm_core(WvT + (long)i0 * 512, 512, in_bf + (long)z * TD + (long)j0 * 512, 512, 512, sm, acc);
#pragma unroll
        for (int r2 = 0; r2 < 4; ++r2)
#pragma unroll
            for (int c2 = 0; c2 < 4; ++c2) {
                const int gi = i0 + wm + r2 * 16 + quad * 4;
                const int gj = j0 + wn + c2 * 16 + lr;
#pragma unroll
                for (int tt = 0; tt < 4; ++tt)
                    vT[(long)z * DT + (long)(gi + tt) * 2048 + gj] = f2bf(acc[r2][c2][tt]);
            }
    } else {                                  // rk = pe @ Wrel
        const int r = t - 1536;
        const int it = r >> 2, jt = r & 3;
        const int i0 = it * 128, j0 = jt * 128;
        gemm_core(pe + (long)i0 * 512, 512, WrT + (long)j0 * 512, 512, 512, sm, acc);
#pragma unroll
        for (int r2 = 0; r2 < 4; ++r2)
#pragma unroll
            for (int c2 = 0; c2 < 4; ++c2) {
                const int gi = i0 + wm + r2 * 16 + quad * 4;
                const int gj = j0 + wn + c2 * 16 + lr;
#pragma unroll
                for (int tt = 0; tt < 4; ++tt)
                    rk[(long)(gi + tt) * 512 + gj] = f2bf(acc[r2][c2][tt]);
            }
    }
}

__global__ __launch_bounds__(256) void score_kernel(
    const unsigned short* __restrict__ qc, const unsigned short* __restrict__ kbf,
    float* __restrict__ C8)
{
    __shared__ SMem sm;
    EPI_COORDS();
    const long TD = (long)T_ * D_;
    f32x4 acc[4][4];
    const int t = blockIdx.x;                 // 0..1087 = 8 x 136 causal tiles
    const int z = t / 136;
    const int r = t - z * 136;
    int a = (int)((sqrtf(8.f * (float)r + 1.f) - 1.f) * 0.5f);
    if ((a + 1) * (a + 2) / 2 <= r) ++a;
    if (a * (a + 1) / 2 > r) --a;
    const int b = r - a * (a + 1) / 2;        // b <= a
    const int i0 = a * 128, j0 = b * 128;
    gemm_core(qc + (long)z * TD + (long)i0 * 512, 512,
              kbf + (long)z * TD + (long)j0 * 512, 512, 512, sm, acc);
    float* Cf = C8 + (long)z * 4194304L;
#pragma unroll
    for (int r2 = 0; r2 < 4; ++r2)
#pragma unroll
        for (int c2 = 0; c2 < 4; ++c2) {
            const int gi = i0 + wm + r2 * 16 + quad * 4;
            const int gj = j0 + wn + c2 * 16 + lr;
#pragma unroll
            for (int tt = 0; tt < 4; ++tt)
                Cf[(long)(gi + tt) * 2048 + gj] = acc[r2][c2][tt] * SC_;
        }
}

__global__ __launch_bounds__(256) void radd_kernel(
    const unsigned short* __restrict__ qr, const unsigned short* __restrict__ rk,
    float* __restrict__ C8)
{
    __shared__ SMem sm;
    EPI_COORDS();
    const long TD = (long)T_ * D_;
    f32x4 acc[4][4];
    const int t = blockIdx.x;                 // 0..1087
    const int z = t / 136;
    const int r = t - z * 136;
    int u = (int)((sqrtf(8.f * (float)r + 1.f) - 1.f) * 0.5f);
    if ((u + 1) * (u + 2) / 2 <= r) ++u;
    if (u * (u + 1) / 2 > r) --u;
    const int v2 = r - u * (u + 1) / 2;       // v2 <= u
    const int a = u, b = 15 - u + v2;         // a+b >= 15 (tiles with shift targets)
    const int i0 = a * 128, p0 = b * 128;
    gemm_core(qr + (long)z * TD + (long)i0 * 512, 512,
              rk + (long)p0 * 512, 512, 512, sm, acc);
    float* Cf = C8 + (long)z * 4194304L;
#pragma unroll
    for (int r2 = 0; r2 < 4; ++r2)
#pragma unroll
        for (int c2 = 0; c2 < 4; ++c2) {
            const int gi = i0 + wm + r2 * 16 + quad * 4;
            const int gp = p0 + wn + c2 * 16 + lr;
#pragma unroll
            for (int tt = 0; tt < 4; ++tt) {
                const int row = gi + tt;
                const int j = row + gp - (T_ - 1);   // R[i,p] -> C[i, i+p-(T-1)]
                if (j >= 0) Cf[(long)row * 2048 + j] += acc[r2][c2][tt] * SC_;
            }
        }
}

// row softmax -> P (bf16 in place); scores pre-scaled by 1/sqrt(D)
__global__ __launch_bounds__(256) void softmax_kernel(float* __restrict__ C8) {
    float* Cm = C8 + (long)blockIdx.y * 4194304L;
    const int i = blockIdx.x;
    const int n = i + 1;
    __shared__ float s[2048];
    __shared__ float red[8];
    const int tid = threadIdx.x;
    const int wid = tid >> 6;
    float* row = Cm + (long)i * 2048;
    float lmax = -3.0e38f;
    for (int j = tid; j < n; j += 256) { float v = row[j]; s[j] = v; lmax = fmaxf(lmax, v); }
    for (int o = 32; o; o >>= 1) lmax = fmaxf(lmax, __shfl_down(lmax, o));
    if ((tid & 63) == 0) red[wid] = lmax;
    __syncthreads();
    if (tid == 0) red[4] = fmaxf(fmaxf(red[0], red[1]), fmaxf(red[2], red[3]));
    __syncthreads();
    const float m = red[4];
    float lsum = 0.f;
    for (int j = tid; j < n; j += 256) { float e = __expf(s[j] - m); s[j] = e; lsum += e; }
    for (int o = 32; o; o >>= 1) lsum += __shfl_down(lsum, o);
    __syncthreads();
    if ((tid & 63) == 0) red[wid] = lsum;
    __syncthreads();
    if (tid == 0) red[4] = 1.0f / (red[0] + red[1] + red[2] + red[3]);
    __syncthreads();
    const float inv = red[4];
    unsigned short* P = (unsigned short*)Cm;          // bf16 row stride 4096
    const int iend = ((i >> 7) + 1) << 7;             // zero-pad to 128-tile edge
    for (int j = tid; j < iend; j += 256) {
        const float pv = (j < n) ? s[j] * inv : 0.f;
        P[(long)i * 4096 + j] = f2bf(pv);
    }
}

__global__ __launch_bounds__(256) void pv_kernel(
    const float* __restrict__ C8, const unsigned short* __restrict__ vT,
    float* __restrict__ out)
{
    __shared__ SMem sm;
    EPI_COORDS();
    const long TD = (long)T_ * D_;
    const long DT = (long)D_ * T_;
    f32x4 acc[4][4];
    const int t = blockIdx.x;                 // 0..511
    const int z = t >> 6;
    const int rr = t & 63;
    const int it = rr >> 2, jt = rr & 3;
    const int i0 = it * 128, j0 = jt * 128;
    const int kmax = i0 + 128;                // causal K-limit
    gemm_core((const unsigned short*)(C8 + (long)z * 4194304L) + (long)i0 * 4096, 4096,
              vT + (long)z * DT + (long)j0 * 2048, 2048, kmax, sm, acc);
#pragma unroll
    for (int r2 = 0; r2 < 4; ++r2)
#pragma unroll
        for (int c2 = 0; c2 < 4; ++c2) {
            const int gi = i0 + wm + r2 * 16 + quad * 4;
            const int gj = j0 + wn + c2 * 16 + lr;
#pragma unroll
            for (int tt = 0; tt < 4; ++tt)
                out[(long)z * TD + (long)(gi + tt) * 512 + gj] = acc[r2][c2][tt];
        }
}

// ---------------------------------------------------------------- launcher
extern "C" void kernel_launch(void* const* d_in, const int* in_sizes, int n_in,
                              void* d_out, int out_size, void* d_ws, size_t ws_size,
                              hipStream_t stream) {
    (void)in_sizes; (void)n_in; (void)out_size; (void)ws_size;
    const float* inputs = (const float*)d_in[0];
    const float* Wq = (const float*)d_in[1];
    const float* Wk = (const float*)d_in[2];
    const float* Wv = (const float*)d_in[3];
    const float* Wrel = (const float*)d_in[4];
    const float* cb = (const float*)d_in[5];
    const float* rb = (const float*)d_in[6];
    float* out = (float*)d_out;

    // workspace layout (~224 MB)
    char* ws = (char*)d_ws;
    unsigned short* in_bf = (unsigned short*)ws;                   // 16384x512
    unsigned short* WqT = (unsigned short*)(ws + 16777216);
    unsigned short* WkT = WqT + 262144;
    unsigned short* WvT = WkT + 262144;
    unsigned short* WrT = WvT + 262144;
    unsigned short* pe  = WrT + 262144;                            // 2048x512
    unsigned short* qc  = pe + 1048576;                            // 16384x512
    unsigned short* qr  = qc + 8388608;
    unsigned short* kbf = qr + 8388608;
    unsigned short* vT  = kbf + 8388608;                           // 8 x 512x2048
    unsigned short* rk  = vT + 8388608;                            // 2048x512
    float* C8 = (float*)(rk + 1048576);                            // 8 x 2048x2048 f32

    prep_convert<<<dim3(8192), 256, 0, stream>>>(inputs, in_bf);
    prep_w<<<dim3(1024, 4), 256, 0, stream>>>(Wq, Wk, Wv, Wrel, WqT, WkT, WvT, WrT);
    prep_pe<<<dim3(4096), 256, 0, stream>>>(pe);

    proj_kernel<<<dim3(1600), 256, 0, stream>>>(in_bf, WqT, WkT, WvT, WrT, pe, cb, rb,
                                                qc, qr, kbf, vT, rk);
    score_kernel<<<dim3(1088), 256, 0, stream>>>(qc, kbf, C8);
    radd_kernel<<<dim3(1088), 256, 0, stream>>>(qr, rk, C8);
    softmax_kernel<<<dim3(2048, 8), 256, 0, stream>>>(C8);
    pv_kernel<<<dim3(512), 256, 0, stream>>>(C8, vT, out);
}